// Round 1
// baseline (791.316 us; speedup 1.0000x reference)
//
#include <hip/hip_runtime.h>
#include <stdint.h>

#define N_NODES 100000
#define N_EDGES 1600000
#define NB_SCAN 391   // ceil(N_NODES/256)

// Round 16. r15: 645 us. Counters: k_scatter_ew WRITE_SIZE=302MB vs 32MB
// payload (5 scattered 4B stores/edge -> 5 lines/edge); dur == 302MB/2.2TB/s
// -> pure write-line bound. Agg kernels VALUBusy 52%, BW 8% -> issue/latency
// bound at 2 edges per gather inst.
// Changes: (1) scatter writes ONE 16B struct/edge {src, ea0, ea1, pad} ->
// 1 line/edge (~100MB); ew4 buffer dropped; edge-MLP recomputed per layer in
// the agg from exact fp32 edge_attr (bitwise-identical ew -> absmax unchanged).
// (2) agg restructured to dwordx4 gathers: lane reads 16B (8 ch) of one row,
// 8 lanes/row -> 8 edges/gather inst (1KB/wave), 2-deep load pipeline,
// shfl_xor(8/16/32) butterfly epilogue. ws ~53 MB (< 78.2 proven).

__device__ __forceinline__ float bf2f(unsigned short s) {
    return __uint_as_float(((unsigned)s) << 16);
}
__device__ __forceinline__ unsigned short f2bf(float f) {
    unsigned u = __float_as_uint(f);
    u += 0x7fffu + ((u >> 16) & 1u);
    return (unsigned short)(u >> 16);
}
template <bool BF16>
__device__ __forceinline__ float LD(const void* p, size_t i) {
    if (BF16) return bf2f(((const unsigned short*)p)[i]);
    return ((const float*)p)[i];
}

// ---------------- dtype detection (proven) ----------------
__global__ void k_detect(const unsigned* __restrict__ xw, int* __restrict__ flag) {
    __shared__ int tot;
    if (threadIdx.x == 0) tot = 0;
    __syncthreads();
    int hit = 0;
    for (int i = threadIdx.x; i < 1024; i += 256) {
        unsigned e = (xw[i] >> 7) & 0xFFu;
        if (e >= 110u && e <= 135u) hit++;
    }
    atomicAdd(&tot, hit);
    __syncthreads();
    if (threadIdx.x == 0) *flag = (tot >= 512) ? 1 : 0;
}

// ---------------- CSR build ----------------

__global__ void k_hist(const int* __restrict__ ei, int* __restrict__ deg) {
    int e = blockIdx.x * 256 + threadIdx.x;
    if (e < N_EDGES) atomicAdd(&deg[ei[N_EDGES + e]], 1);
}

__global__ void k_scan_partial(const int* __restrict__ deg, int* __restrict__ bsum) {
    int t = threadIdx.x;
    int i = blockIdx.x * 256 + t;
    int v = (i < N_NODES) ? deg[i] : 0;
    for (int off = 32; off > 0; off >>= 1) v += __shfl_down(v, off, 64);
    __shared__ int ws4[4];
    if ((t & 63) == 0) ws4[t >> 6] = v;
    __syncthreads();
    if (t == 0) bsum[blockIdx.x] = ws4[0] + ws4[1] + ws4[2] + ws4[3];
}

__global__ void k_scan_mid(const int* __restrict__ bsum, int* __restrict__ boff) {
    __shared__ int s[512];
    int t = threadIdx.x;
    int v = (t < NB_SCAN) ? bsum[t] : 0;
    s[t] = v;
    __syncthreads();
    for (int off = 1; off < 512; off <<= 1) {
        int x = (t >= off) ? s[t - off] : 0;
        __syncthreads();
        s[t] += x;
        __syncthreads();
    }
    if (t < NB_SCAN) boff[t] = s[t] - v;   // exclusive
}

__global__ void k_scan_final(const int* __restrict__ deg, const int* __restrict__ boff,
                             int* __restrict__ row_start, int* __restrict__ cursor) {
    __shared__ int s[256];
    int t = threadIdx.x;
    int i = blockIdx.x * 256 + t;
    int v = (i < N_NODES) ? deg[i] : 0;
    s[t] = v;
    __syncthreads();
    for (int off = 1; off < 256; off <<= 1) {
        int x = (t >= off) ? s[t - off] : 0;
        __syncthreads();
        s[t] += x;
        __syncthreads();
    }
    if (i < N_NODES) {
        int rs = boff[blockIdx.x] + s[t] - v;
        row_start[i] = rs;
        cursor[i] = rs;
    }
}

// ---------------- CSR scatter: ONE 16B packed write per edge ----------------

template <bool BF>
__device__ __forceinline__ void scatter_body(const int* __restrict__ ei,
                                             const void* __restrict__ ea,
                                             int* __restrict__ cursor,
                                             uint4* __restrict__ csr_edge) {
    int e = blockIdx.x * 256 + threadIdx.x;   // grid exact: 6250*256 = 1.6M
    int s = ei[e];
    int d = ei[N_EDGES + e];
    float a0 = LD<BF>(ea, (size_t)e * 2);
    float a1 = LD<BF>(ea, (size_t)e * 2 + 1);
    int slot = atomicAdd(&cursor[d], 1);
    csr_edge[slot] = make_uint4((unsigned)s, __float_as_uint(a0), __float_as_uint(a1), 0u);
}

__global__ void k_scatter(const int* __restrict__ flag, const int* ei, const void* ea,
                          int* cursor, uint4* csr_edge) {
    if (*flag) scatter_body<true>(ei, ea, cursor, csr_edge);
    else       scatter_body<false>(ei, ea, cursor, csr_edge);
}

// ---------------- layer 0 dense ----------------

template <bool BF>
__device__ __forceinline__ void dense0_body(const void* __restrict__ x,
                                            const void* __restrict__ W,
                                            const void* __restrict__ b,
                                            unsigned short* __restrict__ h,
                                            float* Wl, float (*xl)[32]) {
    int t = threadIdx.x, w = t >> 6, lane = t & 63;
    for (int i = t; i < 32 * 64; i += 256) Wl[i] = LD<BF>(W, i);
    int v0 = blockIdx.x * 16 + w * 4;
    if (lane < 32) {
        #pragma unroll
        for (int n = 0; n < 4; n++)
            xl[w * 4 + n][lane] = LD<BF>(x, (size_t)(v0 + n) * 32 + lane);
    }
    __syncthreads();
    float bias = LD<BF>(b, lane);
    float a0 = bias, a1 = bias, a2 = bias, a3 = bias;
    #pragma unroll 8
    for (int k = 0; k < 32; k++) {
        float wv = Wl[k * 64 + lane];
        a0 = fmaf(xl[w * 4 + 0][k], wv, a0);
        a1 = fmaf(xl[w * 4 + 1][k], wv, a1);
        a2 = fmaf(xl[w * 4 + 2][k], wv, a2);
        a3 = fmaf(xl[w * 4 + 3][k], wv, a3);
    }
    h[(size_t)(v0 + 0) * 64 + lane] = f2bf(a0);
    h[(size_t)(v0 + 1) * 64 + lane] = f2bf(a1);
    h[(size_t)(v0 + 2) * 64 + lane] = f2bf(a2);
    h[(size_t)(v0 + 3) * 64 + lane] = f2bf(a3);
}

__global__ void k_dense0(const int* __restrict__ flag, const void* x, const void* W,
                         const void* b, unsigned short* h) {
    __shared__ float Wl[32 * 64];
    __shared__ float xl[16][32];
    if (*flag) dense0_body<true>(x, W, b, h, Wl, xl);
    else       dense0_body<false>(x, W, b, h, Wl, xl);
}

// ---------------- aggregation: dwordx4 gathers, 8 edges / instruction ------
// h rows = 8 x uint4 (16B = 8 bf16 channels). Lane L: edge group g = L>>3,
// channel quad co = L&7 (channels 8*co .. 8*co+7). One gather inst fetches
// 8 full rows (1 KB/wave). Edge MLP computed in-lane from exact fp32 ea at
// chunk-load time (bitwise-identical to precomputed ew). Butterfly
// shfl_xor(8/16/32) sums the 8 edge groups; lanes 0-7 then hold the full row.

__device__ __forceinline__ void agg_node8(int st, int d,
                                          const uint4* __restrict__ csr_edge,
                                          const uint4* __restrict__ hu4,
                                          int lane,
                                          const float* __restrict__ s_mw1,
                                          const float* __restrict__ s_mb1,
                                          const float* __restrict__ s_mw2,
                                          float mb2,
                                          float* acc) {
    int g = lane >> 3;
    int co = lane & 7;
    #pragma unroll
    for (int k = 0; k < 8; k++) acc[k] = 0.f;
    for (int base = 0; base < d; base += 64) {
        int cnt = min(64, d - base);
        int idx = 0;
        float ev = 0.f;
        if (lane < cnt) {
            uint4 u = csr_edge[st + base + lane];
            idx = (int)u.x;
            float a0 = __uint_as_float(u.y);
            float a1 = __uint_as_float(u.z);
            float z0 = mb2, z1 = 0.f, z2 = 0.f, z3 = 0.f;
            #pragma unroll
            for (int q = 0; q < 4; q++) {
                float h0 = fmaf(a0, s_mw1[q],      fmaf(a1, s_mw1[16 + q],      s_mb1[q]));
                float h1 = fmaf(a0, s_mw1[4 + q],  fmaf(a1, s_mw1[20 + q],  s_mb1[4 + q]));
                float h2 = fmaf(a0, s_mw1[8 + q],  fmaf(a1, s_mw1[24 + q],  s_mb1[8 + q]));
                float h3 = fmaf(a0, s_mw1[12 + q], fmaf(a1, s_mw1[28 + q], s_mb1[12 + q]));
                z0 = fmaf(fmaxf(h0, 0.f), s_mw2[q], z0);
                z1 = fmaf(fmaxf(h1, 0.f), s_mw2[4 + q], z1);
                z2 = fmaf(fmaxf(h2, 0.f), s_mw2[8 + q], z2);
                z3 = fmaf(fmaxf(h3, 0.f), s_mw2[12 + q], z3);
            }
            float z = (z0 + z1) + (z2 + z3);
            ev = 1.f / (1.f + expf(-z));
        }
        for (int j = 0; j < cnt; j += 16) {
            int sA = __shfl(idx, j + g, 64);
            float eA = __shfl(ev, j + g, 64);
            int sB = __shfl(idx, j + 8 + g, 64);
            float eB = __shfl(ev, j + 8 + g, 64);
            uint4 hA = hu4[(size_t)sA * 8 + co];
            uint4 hB = hu4[(size_t)sB * 8 + co];
            acc[0] = fmaf(eA, __uint_as_float(hA.x << 16), acc[0]);
            acc[1] = fmaf(eA, __uint_as_float(hA.x & 0xffff0000u), acc[1]);
            acc[2] = fmaf(eA, __uint_as_float(hA.y << 16), acc[2]);
            acc[3] = fmaf(eA, __uint_as_float(hA.y & 0xffff0000u), acc[3]);
            acc[4] = fmaf(eA, __uint_as_float(hA.z << 16), acc[4]);
            acc[5] = fmaf(eA, __uint_as_float(hA.z & 0xffff0000u), acc[5]);
            acc[6] = fmaf(eA, __uint_as_float(hA.w << 16), acc[6]);
            acc[7] = fmaf(eA, __uint_as_float(hA.w & 0xffff0000u), acc[7]);
            acc[0] = fmaf(eB, __uint_as_float(hB.x << 16), acc[0]);
            acc[1] = fmaf(eB, __uint_as_float(hB.x & 0xffff0000u), acc[1]);
            acc[2] = fmaf(eB, __uint_as_float(hB.y << 16), acc[2]);
            acc[3] = fmaf(eB, __uint_as_float(hB.y & 0xffff0000u), acc[3]);
            acc[4] = fmaf(eB, __uint_as_float(hB.z << 16), acc[4]);
            acc[5] = fmaf(eB, __uint_as_float(hB.z & 0xffff0000u), acc[5]);
            acc[6] = fmaf(eB, __uint_as_float(hB.w << 16), acc[6]);
            acc[7] = fmaf(eB, __uint_as_float(hB.w & 0xffff0000u), acc[7]);
        }
    }
    #pragma unroll
    for (int m = 8; m <= 32; m <<= 1) {
        #pragma unroll
        for (int k = 0; k < 8; k++) acc[k] += __shfl_xor(acc[k], m, 64);
    }
}

// ---------------- fused: x = relu(agg(h_in)); h_out = x @ W + b ----------------
// 8 nodes/block (4 waves x 2 nodes); x fp32 in LDS only

template <bool BF>
__device__ __forceinline__ void fuse_body(const int* row_start, const int* deg,
                                          const uint4* __restrict__ csr_edge,
                                          const uint4* __restrict__ hu4,
                                          const void* W, int Woff, const void* b, int boff,
                                          const void* ew1, const void* eb1,
                                          const void* ew2, const void* eb2, int l,
                                          unsigned short* h_out,
                                          float* Wl, float (*xs)[64],
                                          float* s_mw1, float* s_mb1, float* s_mw2,
                                          float* s_mb2) {
    int t = threadIdx.x, w = t >> 6, lane = t & 63;
    if (t < 32) s_mw1[t] = LD<BF>(ew1, l * 32 + t);
    else if (t < 48) s_mb1[t - 32] = LD<BF>(eb1, l * 16 + t - 32);
    else if (t < 64) s_mw2[t - 48] = LD<BF>(ew2, l * 16 + t - 48);
    else if (t == 64) s_mb2[0] = LD<BF>(eb2, l);
    for (int i = t; i < 64 * 64; i += 256) Wl[i] = LD<BF>(W, Woff + i);
    __syncthreads();
    float mb2 = s_mb2[0];
    int v0 = blockIdx.x * 8 + w * 2;
    float acc[8];
    #pragma unroll
    for (int n = 0; n < 2; n++) {
        agg_node8(row_start[v0 + n], deg[v0 + n], csr_edge, hu4, lane,
                  s_mw1, s_mb1, s_mw2, mb2, acc);
        if (lane < 8) {
            #pragma unroll
            for (int k = 0; k < 8; k++)
                xs[w * 2 + n][lane * 8 + k] = fmaxf(acc[k], 0.f);   // relu after agg
        }
    }
    __syncthreads();
    float bias = LD<BF>(b, boff + lane);
    float a0 = bias, a1 = bias;
    #pragma unroll 8
    for (int k = 0; k < 64; k++) {
        float wv = Wl[k * 64 + lane];
        a0 = fmaf(xs[w * 2 + 0][k], wv, a0);
        a1 = fmaf(xs[w * 2 + 1][k], wv, a1);
    }
    h_out[(size_t)(v0 + 0) * 64 + lane] = f2bf(a0);
    h_out[(size_t)(v0 + 1) * 64 + lane] = f2bf(a1);
}

__global__ void k_fuse(const int* __restrict__ flag,
                       const int* row_start, const int* deg,
                       const uint4* __restrict__ csr_edge, const void* hu,
                       const void* W, int Woff, const void* b, int boff,
                       const void* ew1, const void* eb1, const void* ew2, const void* eb2,
                       int l, unsigned short* h_out) {
    __shared__ float Wl[64 * 64];
    __shared__ float xs[8][64];
    __shared__ float s_mw1[32], s_mb1[16], s_mw2[16], s_mb2[1];
    if (*flag)
        fuse_body<true>(row_start, deg, csr_edge, (const uint4*)hu, W, Woff, b, boff,
                        ew1, eb1, ew2, eb2, l, h_out, Wl, xs, s_mw1, s_mb1, s_mw2, s_mb2);
    else
        fuse_body<false>(row_start, deg, csr_edge, (const uint4*)hu, W, Woff, b, boff,
                         ew1, eb1, ew2, eb2, l, h_out, Wl, xs, s_mw1, s_mb1, s_mw2, s_mb2);
}

// ---------------- fused final: x3 = relu(agg(h3)); heads -> out ---------------
// 16 nodes/block (4 waves x 4 nodes)

template <bool BF>
__device__ __forceinline__ void fuse_heads_body(
        const int* row_start, const int* deg,
        const uint4* __restrict__ csr_edge, const uint4* __restrict__ hu4,
        const void* rh1w, const void* rh1b, const void* rh2w, const void* rh2b,
        const void* meanw, const void* meanb, const void* stdw, const void* stdb,
        const void* cls1w, const void* cls1b, const void* cls2w, const void* cls2b,
        const void* ew1, const void* eb1, const void* ew2, const void* eb2,
        void* __restrict__ out,
        float* s_rh1, float* s_cls1, float* s_rh2, float* s_cls2,
        float* s_rh1b, float* s_cls1b, float* s_rh2b, float* s_mw, float* s_sw,
        float* s_c2b, float* s_msb,
        float* s_mw1, float* s_mb1, float* s_mw2, float* s_mb2,
        float (*xs)[64], float (*r1)[32], float (*c1h)[32], float (*r2)[16]) {
    int t = threadIdx.x, w = t >> 6, lane = t & 63;
    for (int i = t; i < 2048; i += 256) { s_rh1[i] = LD<BF>(rh1w, i); s_cls1[i] = LD<BF>(cls1w, i); }
    for (int i = t; i < 512; i += 256) s_rh2[i] = LD<BF>(rh2w, i);
    if (t < 64) s_cls2[t] = LD<BF>(cls2w, t);
    if (t < 32) { s_rh1b[t] = LD<BF>(rh1b, t); s_cls1b[t] = LD<BF>(cls1b, t); }
    else if (t < 48) { int i = t - 32; s_rh2b[i] = LD<BF>(rh2b, i); s_mw[i] = LD<BF>(meanw, i); s_sw[i] = LD<BF>(stdw, i); }
    else if (t == 48) { s_msb[0] = LD<BF>(meanb, 0); s_msb[1] = LD<BF>(stdb, 0); }
    else if (t == 49) { s_c2b[0] = LD<BF>(cls2b, 0); s_c2b[1] = LD<BF>(cls2b, 1); }
    // layer-3 edge-MLP weights
    if (t >= 64 && t < 96) s_mw1[t - 64] = LD<BF>(ew1, 96 + t - 64);
    else if (t >= 96 && t < 112) s_mb1[t - 96] = LD<BF>(eb1, 48 + t - 96);
    else if (t >= 112 && t < 128) s_mw2[t - 112] = LD<BF>(ew2, 48 + t - 112);
    else if (t == 128) s_mb2[0] = LD<BF>(eb2, 3);
    __syncthreads();

    float mb2 = s_mb2[0];
    int v00 = blockIdx.x * 16;
    float acc[8];
    #pragma unroll
    for (int n = 0; n < 4; n++) {
        int idx = w * 4 + n;
        int v = v00 + idx;
        agg_node8(row_start[v], deg[v], csr_edge, hu4, lane,
                  s_mw1, s_mb1, s_mw2, mb2, acc);
        if (lane < 8) {
            #pragma unroll
            for (int k = 0; k < 8; k++)
                xs[idx][lane * 8 + k] = fmaxf(acc[k], 0.f);
        }
    }
    __syncthreads();

    #pragma unroll
    for (int n = 0; n < 4; n++) {
        int idx = w * 4 + n;
        int c = lane & 31;
        const float* Wp = (lane < 32) ? s_rh1 : s_cls1;
        float a = (lane < 32) ? s_rh1b[c] : s_cls1b[c];
        #pragma unroll 8
        for (int k = 0; k < 64; k++) a = fmaf(xs[idx][k], Wp[k * 32 + c], a);
        a = fmaxf(a, 0.f);
        if (lane < 32) r1[idx][c] = a; else c1h[idx][c] = a;
    }
    __syncthreads();

    #pragma unroll
    for (int n = 0; n < 4; n++) {
        int idx = w * 4 + n;
        if (lane < 16) {
            float a = s_rh2b[lane];
            #pragma unroll
            for (int k = 0; k < 32; k++) a = fmaf(r1[idx][k], s_rh2[k * 16 + lane], a);
            r2[idx][lane] = fmaxf(a, 0.f);
        }
    }
    __syncthreads();

    #pragma unroll
    for (int n = 0; n < 4; n++) {
        int idx = w * 4 + n;
        int v = v00 + idx;
        if (lane == 0) {
            float m = s_msb[0];
            #pragma unroll
            for (int k = 0; k < 16; k++) m = fmaf(r2[idx][k], s_mw[k], m);
            if (BF) ((unsigned short*)out)[v] = f2bf(m); else ((float*)out)[v] = m;
        } else if (lane == 1) {
            float sv = s_msb[1];
            #pragma unroll
            for (int k = 0; k < 16; k++) sv = fmaf(r2[idx][k], s_sw[k], sv);
            float sp = fmaxf(sv, 0.f) + log1pf(expf(-fabsf(sv)));   // stable softplus
            if (BF) ((unsigned short*)out)[N_NODES + v] = f2bf(sp); else ((float*)out)[N_NODES + v] = sp;
        } else if (lane < 4) {
            int jj = lane - 2;
            float a = s_c2b[jj];
            #pragma unroll
            for (int k = 0; k < 32; k++) a = fmaf(c1h[idx][k], s_cls2[k * 2 + jj], a);
            size_t pos = (size_t)2 * N_NODES + (size_t)v * 2 + jj;
            if (BF) ((unsigned short*)out)[pos] = f2bf(a); else ((float*)out)[pos] = a;
        }
    }
}

__global__ void k_fuse_heads(const int* __restrict__ flag,
                             const int* row_start, const int* deg,
                             const uint4* __restrict__ csr_edge, const void* hu,
                             const void* rh1w, const void* rh1b, const void* rh2w, const void* rh2b,
                             const void* meanw, const void* meanb, const void* stdw, const void* stdb,
                             const void* cls1w, const void* cls1b, const void* cls2w, const void* cls2b,
                             const void* ew1, const void* eb1, const void* ew2, const void* eb2,
                             void* out) {
    __shared__ float s_rh1[64 * 32], s_cls1[64 * 32], s_rh2[32 * 16], s_cls2[32 * 2];
    __shared__ float s_rh1b[32], s_cls1b[32], s_rh2b[16], s_mw[16], s_sw[16], s_c2b[2], s_msb[2];
    __shared__ float s_mw1[32], s_mb1[16], s_mw2[16], s_mb2[1];
    __shared__ float xs[16][64], r1[16][32], c1h[16][32], r2[16][16];
    if (*flag)
        fuse_heads_body<true>(row_start, deg, csr_edge, (const uint4*)hu,
                              rh1w, rh1b, rh2w, rh2b, meanw, meanb, stdw, stdb,
                              cls1w, cls1b, cls2w, cls2b, ew1, eb1, ew2, eb2, out,
                              s_rh1, s_cls1, s_rh2, s_cls2, s_rh1b, s_cls1b, s_rh2b,
                              s_mw, s_sw, s_c2b, s_msb, s_mw1, s_mb1, s_mw2, s_mb2,
                              xs, r1, c1h, r2);
    else
        fuse_heads_body<false>(row_start, deg, csr_edge, (const uint4*)hu,
                               rh1w, rh1b, rh2w, rh2b, meanw, meanb, stdw, stdb,
                               cls1w, cls1b, cls2w, cls2b, ew1, eb1, ew2, eb2, out,
                               s_rh1, s_cls1, s_rh2, s_cls2, s_rh1b, s_cls1b, s_rh2b,
                               s_mw, s_sw, s_c2b, s_msb, s_mw1, s_mb1, s_mw2, s_mb2,
                               xs, r1, c1h, r2);
}

// ---------------- launch ----------------

extern "C" void kernel_launch(void* const* d_in, const int* in_sizes, int n_in,
                              void* d_out, int out_size, void* d_ws, size_t ws_size,
                              hipStream_t stream) {
    const void* x_in  = d_in[0];
    const int* ei     = (const int*)d_in[1];
    const void* ea    = d_in[2];
    const void* W0    = d_in[3];
    const void* b0    = d_in[4];
    const void* Ws    = d_in[5];
    const void* bs    = d_in[6];
    const void* ew1   = d_in[7];
    const void* eb1   = d_in[8];
    const void* ew2   = d_in[9];
    const void* eb2   = d_in[10];
    const void* rh1w  = d_in[11];
    const void* rh1b  = d_in[12];
    const void* rh2w  = d_in[13];
    const void* rh2b  = d_in[14];
    const void* meanw = d_in[15];
    const void* meanb = d_in[16];
    const void* stdw  = d_in[17];
    const void* stdb  = d_in[18];
    const void* cls1w = d_in[19];
    const void* cls1b = d_in[20];
    const void* cls2w = d_in[21];
    const void* cls2b = d_in[22];

    char* wsp = (char*)d_ws;
    auto alloc = [&](size_t bytes) -> char* {
        char* p = wsp;
        wsp += (bytes + 255) & ~(size_t)255;
        return p;
    };
    // footprint ~53 MB (< 78.2 MB proven)
    int* flag       = (int*)alloc(4);
    int* deg        = (int*)alloc((size_t)N_NODES * 4);
    int* row_start  = (int*)alloc((size_t)N_NODES * 4);
    int* cursor     = (int*)alloc((size_t)N_NODES * 4);
    int* bsum       = (int*)alloc((size_t)NB_SCAN * 4);
    int* boff       = (int*)alloc((size_t)NB_SCAN * 4);
    uint4* csr_edge = (uint4*)alloc((size_t)N_EDGES * 16);
    unsigned short* hA = (unsigned short*)alloc((size_t)N_NODES * 64 * 2);
    unsigned short* hB = (unsigned short*)alloc((size_t)N_NODES * 64 * 2);

    k_detect<<<1, 256, 0, stream>>>((const unsigned*)x_in, flag);
    hipMemsetAsync(deg, 0, (size_t)N_NODES * 4, stream);
    k_hist<<<6250, 256, 0, stream>>>(ei, deg);
    k_scan_partial<<<NB_SCAN, 256, 0, stream>>>(deg, bsum);
    k_scan_mid<<<1, 512, 0, stream>>>(bsum, boff);
    k_scan_final<<<NB_SCAN, 256, 0, stream>>>(deg, boff, row_start, cursor);
    k_scatter<<<6250, 256, 0, stream>>>(flag, ei, ea, cursor, csr_edge);

    // h0 = x_in @ W0 + b0
    k_dense0<<<6250, 256, 0, stream>>>(flag, x_in, W0, b0, hA);

    unsigned short* hin = hA;
    unsigned short* hout = hB;
    for (int l = 0; l < 3; l++) {
        k_fuse<<<12500, 256, 0, stream>>>(flag, row_start, deg, csr_edge, hin,
                                          Ws, l * 64 * 64, bs, l * 64,
                                          ew1, eb1, ew2, eb2, l, hout);
        unsigned short* tmp = hin; hin = hout; hout = tmp;
    }
    k_fuse_heads<<<6250, 256, 0, stream>>>(flag, row_start, deg, csr_edge, hin,
                                           rh1w, rh1b, rh2w, rh2b, meanw, meanb,
                                           stdw, stdb, cls1w, cls1b, cls2w, cls2b,
                                           ew1, eb1, ew2, eb2, d_out);
}

// Round 2
// 667.615 us; speedup vs baseline: 1.1853x; 1.1853x over previous
//
#include <hip/hip_runtime.h>
#include <stdint.h>

#define N_NODES 100000
#define N_EDGES 1600000
#define NB_SCAN 391   // ceil(N_NODES/256)

// Round 17. r16 (791 us) post-mortem: packed-scatter fixed the 302MB write
// (k_scatter gone from top-5) but agg kernels regressed: +13MB/kernel edge
// stream (16B vs 8B per edge) and in-loop edge-MLP (expf) doubled VGPR
// (32->64, occ 51->41%) and serialized the gather critical path.
// Changes vs r16: (1) new k_ew streaming pass in CSR-slot order: coalesced
// read csr_edge (16B/slot), writes csr_src (4B) + ew4[4][E] (fp32, coalesced).
// r15's exact MLP math -> bitwise-identical ew -> absmax unchanged.
// (2) agg kernels keep the dwordx4 8-edges/gather scheme but stream
// csr_src+ew (8B/edge) with no MLP/expf in the loop.
// (3) ws: csr_edge aliased with hA+hB (dead after k_ew) -> ~59 MB total.

__device__ __forceinline__ float bf2f(unsigned short s) {
    return __uint_as_float(((unsigned)s) << 16);
}
__device__ __forceinline__ unsigned short f2bf(float f) {
    unsigned u = __float_as_uint(f);
    u += 0x7fffu + ((u >> 16) & 1u);
    return (unsigned short)(u >> 16);
}
template <bool BF16>
__device__ __forceinline__ float LD(const void* p, size_t i) {
    if (BF16) return bf2f(((const unsigned short*)p)[i]);
    return ((const float*)p)[i];
}

// ---------------- dtype detection (proven) ----------------
__global__ void k_detect(const unsigned* __restrict__ xw, int* __restrict__ flag) {
    __shared__ int tot;
    if (threadIdx.x == 0) tot = 0;
    __syncthreads();
    int hit = 0;
    for (int i = threadIdx.x; i < 1024; i += 256) {
        unsigned e = (xw[i] >> 7) & 0xFFu;
        if (e >= 110u && e <= 135u) hit++;
    }
    atomicAdd(&tot, hit);
    __syncthreads();
    if (threadIdx.x == 0) *flag = (tot >= 512) ? 1 : 0;
}

// ---------------- CSR build ----------------

__global__ void k_hist(const int* __restrict__ ei, int* __restrict__ deg) {
    int e = blockIdx.x * 256 + threadIdx.x;
    if (e < N_EDGES) atomicAdd(&deg[ei[N_EDGES + e]], 1);
}

__global__ void k_scan_partial(const int* __restrict__ deg, int* __restrict__ bsum) {
    int t = threadIdx.x;
    int i = blockIdx.x * 256 + t;
    int v = (i < N_NODES) ? deg[i] : 0;
    for (int off = 32; off > 0; off >>= 1) v += __shfl_down(v, off, 64);
    __shared__ int ws4[4];
    if ((t & 63) == 0) ws4[t >> 6] = v;
    __syncthreads();
    if (t == 0) bsum[blockIdx.x] = ws4[0] + ws4[1] + ws4[2] + ws4[3];
}

__global__ void k_scan_mid(const int* __restrict__ bsum, int* __restrict__ boff) {
    __shared__ int s[512];
    int t = threadIdx.x;
    int v = (t < NB_SCAN) ? bsum[t] : 0;
    s[t] = v;
    __syncthreads();
    for (int off = 1; off < 512; off <<= 1) {
        int x = (t >= off) ? s[t - off] : 0;
        __syncthreads();
        s[t] += x;
        __syncthreads();
    }
    if (t < NB_SCAN) boff[t] = s[t] - v;   // exclusive
}

__global__ void k_scan_final(const int* __restrict__ deg, const int* __restrict__ boff,
                             int* __restrict__ row_start, int* __restrict__ cursor) {
    __shared__ int s[256];
    int t = threadIdx.x;
    int i = blockIdx.x * 256 + t;
    int v = (i < N_NODES) ? deg[i] : 0;
    s[t] = v;
    __syncthreads();
    for (int off = 1; off < 256; off <<= 1) {
        int x = (t >= off) ? s[t - off] : 0;
        __syncthreads();
        s[t] += x;
        __syncthreads();
    }
    if (i < N_NODES) {
        int rs = boff[blockIdx.x] + s[t] - v;
        row_start[i] = rs;
        cursor[i] = rs;
    }
}

// ---------------- CSR scatter: ONE 16B packed write per edge ----------------

template <bool BF>
__device__ __forceinline__ void scatter_body(const int* __restrict__ ei,
                                             const void* __restrict__ ea,
                                             int* __restrict__ cursor,
                                             uint4* __restrict__ csr_edge) {
    int e = blockIdx.x * 256 + threadIdx.x;   // grid exact: 6250*256 = 1.6M
    int s = ei[e];
    int d = ei[N_EDGES + e];
    float a0 = LD<BF>(ea, (size_t)e * 2);
    float a1 = LD<BF>(ea, (size_t)e * 2 + 1);
    int slot = atomicAdd(&cursor[d], 1);
    csr_edge[slot] = make_uint4((unsigned)s, __float_as_uint(a0), __float_as_uint(a1), 0u);
}

__global__ void k_scatter(const int* __restrict__ flag, const int* ei, const void* ea,
                          int* cursor, uint4* csr_edge) {
    if (*flag) scatter_body<true>(ei, ea, cursor, csr_edge);
    else       scatter_body<false>(ei, ea, cursor, csr_edge);
}

// ---------------- edge-MLP pass: slot-ordered, fully coalesced ----------------
// Reads csr_edge (16B/slot streaming), writes csr_src (4B) + ew4[4][E] (fp32).
// Exact r15 math -> bitwise-identical ew values.

template <bool BF>
__device__ __forceinline__ void ew_body(const uint4* __restrict__ csr_edge,
                                        const void* ew1, const void* eb1,
                                        const void* ew2, const void* eb2,
                                        int* __restrict__ csr_src,
                                        float* __restrict__ ew4,
                                        float (*w1)[2][16], float (*b1)[16],
                                        float (*w2)[16], float* b2) {
    int t = threadIdx.x;
    if (t < 128) ((float*)w1)[t] = LD<BF>(ew1, t);
    else if (t < 192) ((float*)b1)[t - 128] = LD<BF>(eb1, t - 128);
    else ((float*)w2)[t - 192] = LD<BF>(ew2, t - 192);
    if (t < 4) b2[t] = LD<BF>(eb2, t);
    __syncthreads();

    int e = blockIdx.x * 256 + t;   // grid exact: 6250*256 = 1.6M
    uint4 u = csr_edge[e];
    csr_src[e] = (int)u.x;
    float a0 = __uint_as_float(u.y);
    float a1 = __uint_as_float(u.z);
    #pragma unroll
    for (int l = 0; l < 4; l++) {
        float z = b2[l];
        #pragma unroll
        for (int q = 0; q < 16; q++) {
            float hj = fmaf(a0, w1[l][0][q], fmaf(a1, w1[l][1][q], b1[l][q]));
            z = fmaf(fmaxf(hj, 0.f), w2[l][q], z);
        }
        ew4[(size_t)l * N_EDGES + e] = 1.f / (1.f + expf(-z));
    }
}

__global__ void k_ew(const int* __restrict__ flag, const uint4* __restrict__ csr_edge,
                     const void* ew1, const void* eb1, const void* ew2, const void* eb2,
                     int* csr_src, float* ew4) {
    __shared__ float w1[4][2][16], b1[4][16], w2[4][16], b2[4];
    if (*flag) ew_body<true>(csr_edge, ew1, eb1, ew2, eb2, csr_src, ew4, w1, b1, w2, b2);
    else       ew_body<false>(csr_edge, ew1, eb1, ew2, eb2, csr_src, ew4, w1, b1, w2, b2);
}

// ---------------- layer 0 dense ----------------

template <bool BF>
__device__ __forceinline__ void dense0_body(const void* __restrict__ x,
                                            const void* __restrict__ W,
                                            const void* __restrict__ b,
                                            unsigned short* __restrict__ h,
                                            float* Wl, float (*xl)[32]) {
    int t = threadIdx.x, w = t >> 6, lane = t & 63;
    for (int i = t; i < 32 * 64; i += 256) Wl[i] = LD<BF>(W, i);
    int v0 = blockIdx.x * 16 + w * 4;
    if (lane < 32) {
        #pragma unroll
        for (int n = 0; n < 4; n++)
            xl[w * 4 + n][lane] = LD<BF>(x, (size_t)(v0 + n) * 32 + lane);
    }
    __syncthreads();
    float bias = LD<BF>(b, lane);
    float a0 = bias, a1 = bias, a2 = bias, a3 = bias;
    #pragma unroll 8
    for (int k = 0; k < 32; k++) {
        float wv = Wl[k * 64 + lane];
        a0 = fmaf(xl[w * 4 + 0][k], wv, a0);
        a1 = fmaf(xl[w * 4 + 1][k], wv, a1);
        a2 = fmaf(xl[w * 4 + 2][k], wv, a2);
        a3 = fmaf(xl[w * 4 + 3][k], wv, a3);
    }
    h[(size_t)(v0 + 0) * 64 + lane] = f2bf(a0);
    h[(size_t)(v0 + 1) * 64 + lane] = f2bf(a1);
    h[(size_t)(v0 + 2) * 64 + lane] = f2bf(a2);
    h[(size_t)(v0 + 3) * 64 + lane] = f2bf(a3);
}

__global__ void k_dense0(const int* __restrict__ flag, const void* x, const void* W,
                         const void* b, unsigned short* h) {
    __shared__ float Wl[32 * 64];
    __shared__ float xl[16][32];
    if (*flag) dense0_body<true>(x, W, b, h, Wl, xl);
    else       dense0_body<false>(x, W, b, h, Wl, xl);
}

// ---------------- aggregation: dwordx4 gathers, 8 edges / instruction ------
// h rows = 8 x uint4 (16B = 8 bf16 channels). Lane L: edge group g = L>>3,
// channel quad co = L&7 (channels 8*co .. 8*co+7). One gather inst fetches
// 8 full rows (1 KB/wave). idx/ev streamed from csr_src/ew (8B/edge,
// coalesced). Butterfly shfl_xor(8/16/32) sums the 8 edge groups; lanes 0-7
// then hold the full 64-channel row.

__device__ __forceinline__ void agg_node8(int st, int d,
                                          const int* __restrict__ csr_src,
                                          const float* __restrict__ ew,
                                          const uint4* __restrict__ hu4,
                                          int lane, float* acc) {
    int g = lane >> 3;
    int co = lane & 7;
    #pragma unroll
    for (int k = 0; k < 8; k++) acc[k] = 0.f;
    for (int base = 0; base < d; base += 64) {
        int cnt = min(64, d - base);
        int idx = 0;
        float ev = 0.f;
        if (lane < cnt) {
            idx = csr_src[st + base + lane];
            ev = ew[st + base + lane];
        }
        for (int j = 0; j < cnt; j += 16) {
            int sA = __shfl(idx, j + g, 64);
            float eA = __shfl(ev, j + g, 64);
            uint4 hA = hu4[(size_t)sA * 8 + co];
            acc[0] = fmaf(eA, __uint_as_float(hA.x << 16), acc[0]);
            acc[1] = fmaf(eA, __uint_as_float(hA.x & 0xffff0000u), acc[1]);
            acc[2] = fmaf(eA, __uint_as_float(hA.y << 16), acc[2]);
            acc[3] = fmaf(eA, __uint_as_float(hA.y & 0xffff0000u), acc[3]);
            acc[4] = fmaf(eA, __uint_as_float(hA.z << 16), acc[4]);
            acc[5] = fmaf(eA, __uint_as_float(hA.z & 0xffff0000u), acc[5]);
            acc[6] = fmaf(eA, __uint_as_float(hA.w << 16), acc[6]);
            acc[7] = fmaf(eA, __uint_as_float(hA.w & 0xffff0000u), acc[7]);
            if (j + 8 < cnt) {   // wave-uniform (d, j uniform per wave)
                int sB = __shfl(idx, j + 8 + g, 64);
                float eB = __shfl(ev, j + 8 + g, 64);
                uint4 hB = hu4[(size_t)sB * 8 + co];
                acc[0] = fmaf(eB, __uint_as_float(hB.x << 16), acc[0]);
                acc[1] = fmaf(eB, __uint_as_float(hB.x & 0xffff0000u), acc[1]);
                acc[2] = fmaf(eB, __uint_as_float(hB.y << 16), acc[2]);
                acc[3] = fmaf(eB, __uint_as_float(hB.y & 0xffff0000u), acc[3]);
                acc[4] = fmaf(eB, __uint_as_float(hB.z << 16), acc[4]);
                acc[5] = fmaf(eB, __uint_as_float(hB.z & 0xffff0000u), acc[5]);
                acc[6] = fmaf(eB, __uint_as_float(hB.w << 16), acc[6]);
                acc[7] = fmaf(eB, __uint_as_float(hB.w & 0xffff0000u), acc[7]);
            }
        }
    }
    #pragma unroll
    for (int m = 8; m <= 32; m <<= 1) {
        #pragma unroll
        for (int k = 0; k < 8; k++) acc[k] += __shfl_xor(acc[k], m, 64);
    }
}

// ---------------- fused: x = relu(agg(h_in)); h_out = x @ W + b ----------------
// 8 nodes/block (4 waves x 2 nodes); x fp32 in LDS only

template <bool BF>
__device__ __forceinline__ void fuse_body(const int* row_start, const int* deg,
                                          const int* __restrict__ csr_src,
                                          const float* __restrict__ ew,
                                          const uint4* __restrict__ hu4,
                                          const void* W, int Woff, const void* b, int boff,
                                          unsigned short* h_out,
                                          float* Wl, float (*xs)[64]) {
    int t = threadIdx.x, w = t >> 6, lane = t & 63;
    for (int i = t; i < 64 * 64; i += 256) Wl[i] = LD<BF>(W, Woff + i);
    int v0 = blockIdx.x * 8 + w * 2;
    float acc[8];
    #pragma unroll
    for (int n = 0; n < 2; n++) {
        agg_node8(row_start[v0 + n], deg[v0 + n], csr_src, ew, hu4, lane, acc);
        if (lane < 8) {
            #pragma unroll
            for (int k = 0; k < 8; k++)
                xs[w * 2 + n][lane * 8 + k] = fmaxf(acc[k], 0.f);   // relu after agg
        }
    }
    __syncthreads();
    float bias = LD<BF>(b, boff + lane);
    float a0 = bias, a1 = bias;
    #pragma unroll 8
    for (int k = 0; k < 64; k++) {
        float wv = Wl[k * 64 + lane];
        a0 = fmaf(xs[w * 2 + 0][k], wv, a0);
        a1 = fmaf(xs[w * 2 + 1][k], wv, a1);
    }
    h_out[(size_t)(v0 + 0) * 64 + lane] = f2bf(a0);
    h_out[(size_t)(v0 + 1) * 64 + lane] = f2bf(a1);
}

__global__ void k_fuse(const int* __restrict__ flag,
                       const int* row_start, const int* deg,
                       const int* __restrict__ csr_src, const float* __restrict__ ew,
                       const void* hu,
                       const void* W, int Woff, const void* b, int boff,
                       unsigned short* h_out) {
    __shared__ float Wl[64 * 64];
    __shared__ float xs[8][64];
    if (*flag)
        fuse_body<true>(row_start, deg, csr_src, ew, (const uint4*)hu,
                        W, Woff, b, boff, h_out, Wl, xs);
    else
        fuse_body<false>(row_start, deg, csr_src, ew, (const uint4*)hu,
                         W, Woff, b, boff, h_out, Wl, xs);
}

// ---------------- fused final: x3 = relu(agg(h3)); heads -> out ---------------
// 16 nodes/block (4 waves x 4 nodes)

template <bool BF>
__device__ __forceinline__ void fuse_heads_body(
        const int* row_start, const int* deg,
        const int* __restrict__ csr_src, const float* __restrict__ ew,
        const uint4* __restrict__ hu4,
        const void* rh1w, const void* rh1b, const void* rh2w, const void* rh2b,
        const void* meanw, const void* meanb, const void* stdw, const void* stdb,
        const void* cls1w, const void* cls1b, const void* cls2w, const void* cls2b,
        void* __restrict__ out,
        float* s_rh1, float* s_cls1, float* s_rh2, float* s_cls2,
        float* s_rh1b, float* s_cls1b, float* s_rh2b, float* s_mw, float* s_sw,
        float* s_c2b, float* s_msb,
        float (*xs)[64], float (*r1)[32], float (*c1h)[32], float (*r2)[16]) {
    int t = threadIdx.x, w = t >> 6, lane = t & 63;
    for (int i = t; i < 2048; i += 256) { s_rh1[i] = LD<BF>(rh1w, i); s_cls1[i] = LD<BF>(cls1w, i); }
    for (int i = t; i < 512; i += 256) s_rh2[i] = LD<BF>(rh2w, i);
    if (t < 64) s_cls2[t] = LD<BF>(cls2w, t);
    if (t < 32) { s_rh1b[t] = LD<BF>(rh1b, t); s_cls1b[t] = LD<BF>(cls1b, t); }
    else if (t < 48) { int i = t - 32; s_rh2b[i] = LD<BF>(rh2b, i); s_mw[i] = LD<BF>(meanw, i); s_sw[i] = LD<BF>(stdw, i); }
    else if (t == 48) { s_msb[0] = LD<BF>(meanb, 0); s_msb[1] = LD<BF>(stdb, 0); }
    else if (t == 49) { s_c2b[0] = LD<BF>(cls2b, 0); s_c2b[1] = LD<BF>(cls2b, 1); }

    int v00 = blockIdx.x * 16;
    float acc[8];
    #pragma unroll
    for (int n = 0; n < 4; n++) {
        int idx = w * 4 + n;
        int v = v00 + idx;
        agg_node8(row_start[v], deg[v], csr_src, ew, hu4, lane, acc);
        if (lane < 8) {
            #pragma unroll
            for (int k = 0; k < 8; k++)
                xs[idx][lane * 8 + k] = fmaxf(acc[k], 0.f);
        }
    }
    __syncthreads();

    #pragma unroll
    for (int n = 0; n < 4; n++) {
        int idx = w * 4 + n;
        int c = lane & 31;
        const float* Wp = (lane < 32) ? s_rh1 : s_cls1;
        float a = (lane < 32) ? s_rh1b[c] : s_cls1b[c];
        #pragma unroll 8
        for (int k = 0; k < 64; k++) a = fmaf(xs[idx][k], Wp[k * 32 + c], a);
        a = fmaxf(a, 0.f);
        if (lane < 32) r1[idx][c] = a; else c1h[idx][c] = a;
    }
    __syncthreads();

    #pragma unroll
    for (int n = 0; n < 4; n++) {
        int idx = w * 4 + n;
        if (lane < 16) {
            float a = s_rh2b[lane];
            #pragma unroll
            for (int k = 0; k < 32; k++) a = fmaf(r1[idx][k], s_rh2[k * 16 + lane], a);
            r2[idx][lane] = fmaxf(a, 0.f);
        }
    }
    __syncthreads();

    #pragma unroll
    for (int n = 0; n < 4; n++) {
        int idx = w * 4 + n;
        int v = v00 + idx;
        if (lane == 0) {
            float m = s_msb[0];
            #pragma unroll
            for (int k = 0; k < 16; k++) m = fmaf(r2[idx][k], s_mw[k], m);
            if (BF) ((unsigned short*)out)[v] = f2bf(m); else ((float*)out)[v] = m;
        } else if (lane == 1) {
            float sv = s_msb[1];
            #pragma unroll
            for (int k = 0; k < 16; k++) sv = fmaf(r2[idx][k], s_sw[k], sv);
            float sp = fmaxf(sv, 0.f) + log1pf(expf(-fabsf(sv)));   // stable softplus
            if (BF) ((unsigned short*)out)[N_NODES + v] = f2bf(sp); else ((float*)out)[N_NODES + v] = sp;
        } else if (lane < 4) {
            int jj = lane - 2;
            float a = s_c2b[jj];
            #pragma unroll
            for (int k = 0; k < 32; k++) a = fmaf(c1h[idx][k], s_cls2[k * 2 + jj], a);
            size_t pos = (size_t)2 * N_NODES + (size_t)v * 2 + jj;
            if (BF) ((unsigned short*)out)[pos] = f2bf(a); else ((float*)out)[pos] = a;
        }
    }
}

__global__ void k_fuse_heads(const int* __restrict__ flag,
                             const int* row_start, const int* deg,
                             const int* __restrict__ csr_src, const float* __restrict__ ew,
                             const void* hu,
                             const void* rh1w, const void* rh1b, const void* rh2w, const void* rh2b,
                             const void* meanw, const void* meanb, const void* stdw, const void* stdb,
                             const void* cls1w, const void* cls1b, const void* cls2w, const void* cls2b,
                             void* out) {
    __shared__ float s_rh1[64 * 32], s_cls1[64 * 32], s_rh2[32 * 16], s_cls2[32 * 2];
    __shared__ float s_rh1b[32], s_cls1b[32], s_rh2b[16], s_mw[16], s_sw[16], s_c2b[2], s_msb[2];
    __shared__ float xs[16][64], r1[16][32], c1h[16][32], r2[16][16];
    if (*flag)
        fuse_heads_body<true>(row_start, deg, csr_src, ew, (const uint4*)hu,
                              rh1w, rh1b, rh2w, rh2b, meanw, meanb, stdw, stdb,
                              cls1w, cls1b, cls2w, cls2b, out,
                              s_rh1, s_cls1, s_rh2, s_cls2, s_rh1b, s_cls1b, s_rh2b,
                              s_mw, s_sw, s_c2b, s_msb, xs, r1, c1h, r2);
    else
        fuse_heads_body<false>(row_start, deg, csr_src, ew, (const uint4*)hu,
                               rh1w, rh1b, rh2w, rh2b, meanw, meanb, stdw, stdb,
                               cls1w, cls1b, cls2w, cls2b, out,
                               s_rh1, s_cls1, s_rh2, s_cls2, s_rh1b, s_cls1b, s_rh2b,
                               s_mw, s_sw, s_c2b, s_msb, xs, r1, c1h, r2);
}

// ---------------- launch ----------------

extern "C" void kernel_launch(void* const* d_in, const int* in_sizes, int n_in,
                              void* d_out, int out_size, void* d_ws, size_t ws_size,
                              hipStream_t stream) {
    const void* x_in  = d_in[0];
    const int* ei     = (const int*)d_in[1];
    const void* ea    = d_in[2];
    const void* W0    = d_in[3];
    const void* b0    = d_in[4];
    const void* Ws    = d_in[5];
    const void* bs    = d_in[6];
    const void* ew1   = d_in[7];
    const void* eb1   = d_in[8];
    const void* ew2   = d_in[9];
    const void* eb2   = d_in[10];
    const void* rh1w  = d_in[11];
    const void* rh1b  = d_in[12];
    const void* rh2w  = d_in[13];
    const void* rh2b  = d_in[14];
    const void* meanw = d_in[15];
    const void* meanb = d_in[16];
    const void* stdw  = d_in[17];
    const void* stdb  = d_in[18];
    const void* cls1w = d_in[19];
    const void* cls1b = d_in[20];
    const void* cls2w = d_in[21];
    const void* cls2b = d_in[22];

    char* wsp = (char*)d_ws;
    auto alloc = [&](size_t bytes) -> char* {
        char* p = wsp;
        wsp += (bytes + 255) & ~(size_t)255;
        return p;
    };
    // footprint ~59 MB (< 78.2 MB proven):
    //   csr_edge (25.6 MB) is dead after k_ew -> aliased with hA+hB (12.8+12.8)
    int* flag       = (int*)alloc(4);
    int* deg        = (int*)alloc((size_t)N_NODES * 4);
    int* row_start  = (int*)alloc((size_t)N_NODES * 4);
    int* cursor     = (int*)alloc((size_t)N_NODES * 4);
    int* bsum       = (int*)alloc((size_t)NB_SCAN * 4);
    int* boff       = (int*)alloc((size_t)NB_SCAN * 4);
    int* csr_src    = (int*)alloc((size_t)N_EDGES * 4);
    float* ew4      = (float*)alloc((size_t)4 * N_EDGES * 4);
    char* hreg      = alloc((size_t)N_EDGES * 16);       // union region, 25.6 MB
    uint4* csr_edge = (uint4*)hreg;
    unsigned short* hA = (unsigned short*)hreg;
    unsigned short* hB = (unsigned short*)(hreg + (size_t)N_NODES * 64 * 2);

    k_detect<<<1, 256, 0, stream>>>((const unsigned*)x_in, flag);
    hipMemsetAsync(deg, 0, (size_t)N_NODES * 4, stream);
    k_hist<<<6250, 256, 0, stream>>>(ei, deg);
    k_scan_partial<<<NB_SCAN, 256, 0, stream>>>(deg, bsum);
    k_scan_mid<<<1, 512, 0, stream>>>(bsum, boff);
    k_scan_final<<<NB_SCAN, 256, 0, stream>>>(deg, boff, row_start, cursor);
    k_scatter<<<6250, 256, 0, stream>>>(flag, ei, ea, cursor, csr_edge);
    k_ew<<<6250, 256, 0, stream>>>(flag, csr_edge, ew1, eb1, ew2, eb2, csr_src, ew4);

    // h0 = x_in @ W0 + b0   (hA clobbers csr_edge region -- dead after k_ew)
    k_dense0<<<6250, 256, 0, stream>>>(flag, x_in, W0, b0, hA);

    unsigned short* hin = hA;
    unsigned short* hout = hB;
    for (int l = 0; l < 3; l++) {
        k_fuse<<<12500, 256, 0, stream>>>(flag, row_start, deg, csr_src,
                                          ew4 + (size_t)l * N_EDGES, hin,
                                          Ws, l * 64 * 64, bs, l * 64, hout);
        unsigned short* tmp = hin; hin = hout; hout = tmp;
    }
    k_fuse_heads<<<6250, 256, 0, stream>>>(flag, row_start, deg, csr_src,
                                           ew4 + (size_t)3 * N_EDGES, hin,
                                           rh1w, rh1b, rh2w, rh2b, meanw, meanb,
                                           stdw, stdb, cls1w, cls1b, cls2w, cls2b,
                                           d_out);
}